// Round 7
// baseline (311.988 us; speedup 1.0000x reference)
//
#include <hip/hip_runtime.h>
#include <hip/hip_bf16.h>

#define SEQ 2048
#define HD 128
#define NH 32
#define NKV 8
#define ODIM 4096
#define QB 64
#define KVB 64
#define SCALE 0.08838834764831845f
#define NEGBIG -1e9f

typedef __attribute__((ext_vector_type(8))) short bf16x8;
typedef __attribute__((ext_vector_type(4))) float f32x4;

__device__ __forceinline__ unsigned short f2bf(float x) {
  union { __hip_bfloat16 b; unsigned short u; } c;
  c.b = __float2bfloat16(x);  // RNE, single HW cvt
  return c.u;
}

__device__ __forceinline__ unsigned pack2bf(float lo, float hi) {
  union { __hip_bfloat162 h; unsigned u; } c;
  c.h = __float22bfloat162_rn(float2{lo, hi});  // x=lo (low 16b), y=hi
  return c.u;
}

// Block p handles Q-tiles {p, 31-p}: balanced 33 compute-units per block.
// 8 waves: w<4 -> tile A (qt=p) strip w; w>=4 -> tile B (qt=31-p) strip w-4.
// Pipelined: global loads for tile t+1 issued before compute(t); LDS K/V
// double-buffered so staging writes overlap nothing and 1 barrier/tile.
__global__ __launch_bounds__(512, 4) void sdpa_flash_kernel(
    const float* __restrict__ q, const float* __restrict__ k,
    const float* __restrict__ v, float* __restrict__ out) {
  // LDS: 2 x { K [64][128] bf16 swz (16KB) + V^T [128][64] bf16 swz (16KB) }
  //      + per-wave P buffer [16][64] bf16 (8 x 2KB) = 80KB -> 2 blocks/CU
  __shared__ __align__(16) unsigned char smem[81920];
  const int tid = threadIdx.x;
  const int w = tid >> 6;
  const int l = tid & 63;
  const int lm = l & 15;
  const int lg = l >> 4;
  unsigned char* Plds = smem + 65536 + (w << 11);

  const int p = (int)blockIdx.x;       // 0..15
  const int qtA = p;
  const int qtB = 31 - p;
  const int myqt = (w < 4) ? qtA : qtB;
  const int h = (int)blockIdx.y;
  const int hkv = h >> 2;              // repeat_interleave: kv head = h / 4
  const int qbase = myqt * QB + 16 * (w & 3);

  // ---- Q fragments, pre-scaled by 1/sqrt(D) ----
  // A-frag: lane holds Q[q = lm][d = 32*c + 8*lg + j], j=0..7 contiguous
  bf16x8 qa[4];
  {
    const float* qr = q + ((size_t)(h * SEQ + qbase + lm)) * HD + 8 * lg;
    #pragma unroll
    for (int c = 0; c < 4; ++c) {
      float4 a = *(const float4*)(qr + 32 * c);
      float4 b = *(const float4*)(qr + 32 * c + 4);
      union { unsigned short hh[8]; bf16x8 vv; } pk;
      pk.hh[0] = f2bf(a.x * SCALE); pk.hh[1] = f2bf(a.y * SCALE);
      pk.hh[2] = f2bf(a.z * SCALE); pk.hh[3] = f2bf(a.w * SCALE);
      pk.hh[4] = f2bf(b.x * SCALE); pk.hh[5] = f2bf(b.y * SCALE);
      pk.hh[6] = f2bf(b.z * SCALE); pk.hh[7] = f2bf(b.w * SCALE);
      qa[c] = pk.vv;
    }
  }

  f32x4 o[8];
  #pragma unroll
  for (int i = 0; i < 8; ++i) o[i] = (f32x4){0.f, 0.f, 0.f, 0.f};
  float mrow[4] = {-1e30f, -1e30f, -1e30f, -1e30f};
  float lrow[4] = {0.f, 0.f, 0.f, 0.f};

  const int ntiles = qtB + 1;  // union of both halves' needs
  const float* kg0 = k + (size_t)hkv * SEQ * HD;
  const float* vg0 = v + (size_t)hkv * SEQ * HD;

  // per-thread staging coordinates (constant across tiles)
  const int k_r0 = tid >> 4;           // K rows r0 and r0+32
  const int k_c8 = (tid & 15) << 3;    // K d-start
  const int v_rr = (tid & 31) << 1;    // V even kv row
  const int v_d0 = (tid >> 5) << 3;    // V d-block start

  float4 kra0, krb0, kra1, krb1, vra0, vrb0, vra1, vrb1;

  auto issue_loads = [&](int t) {
    const float* kg = kg0 + (size_t)(t * KVB) * HD;
    const float* vg = vg0 + (size_t)(t * KVB) * HD;
    const float* s0 = kg + k_r0 * HD + k_c8;
    kra0 = *(const float4*)(s0);
    krb0 = *(const float4*)(s0 + 4);
    const float* s1 = s0 + 32 * HD;
    kra1 = *(const float4*)(s1);
    krb1 = *(const float4*)(s1 + 4);
    const float* t0 = vg + v_rr * HD + v_d0;
    vra0 = *(const float4*)(t0);
    vrb0 = *(const float4*)(t0 + 4);
    vra1 = *(const float4*)(t0 + HD);
    vrb1 = *(const float4*)(t0 + HD + 4);
  };

  auto write_lds = [&](unsigned char* Kb, unsigned char* Vb) {
    // K rows k_r0, k_r0+32 : b128 writes, XOR-swizzled
    {
      union { unsigned short hh[8]; uint4 u4; } pk;
      pk.hh[0]=f2bf(kra0.x); pk.hh[1]=f2bf(kra0.y); pk.hh[2]=f2bf(kra0.z); pk.hh[3]=f2bf(kra0.w);
      pk.hh[4]=f2bf(krb0.x); pk.hh[5]=f2bf(krb0.y); pk.hh[6]=f2bf(krb0.z); pk.hh[7]=f2bf(krb0.w);
      int byte = (k_r0 << 8) + ((k_c8 << 1) ^ ((k_r0 & 7) << 4));
      *(uint4*)(Kb + byte) = pk.u4;
    }
    {
      int r1 = k_r0 + 32;
      union { unsigned short hh[8]; uint4 u4; } pk;
      pk.hh[0]=f2bf(kra1.x); pk.hh[1]=f2bf(kra1.y); pk.hh[2]=f2bf(kra1.z); pk.hh[3]=f2bf(kra1.w);
      pk.hh[4]=f2bf(krb1.x); pk.hh[5]=f2bf(krb1.y); pk.hh[6]=f2bf(krb1.z); pk.hh[7]=f2bf(krb1.w);
      int byte = (r1 << 8) + ((k_c8 << 1) ^ ((r1 & 7) << 4));
      *(uint4*)(Kb + byte) = pk.u4;
    }
    // V^T: packed kv-pair b32 writes; bank=(lane&31)^(4j) -> conflict-free
    {
      float lo[8] = {vra0.x,vra0.y,vra0.z,vra0.w,vrb0.x,vrb0.y,vrb0.z,vrb0.w};
      float hi[8] = {vra1.x,vra1.y,vra1.z,vra1.w,vrb1.x,vrb1.y,vrb1.z,vrb1.w};
      #pragma unroll
      for (int j = 0; j < 8; ++j) {
        int d = v_d0 + j;
        int byte = (d << 7) + ((v_rr << 1) ^ ((d & 7) << 4));
        *(unsigned*)(Vb + byte) = pack2bf(lo[j], hi[j]);
      }
    }
  };

  // ---- prologue: stage tile 0 into buffer 0 ----
  issue_loads(0);
  write_lds(smem, smem + 16384);
  __syncthreads();
  int cur = 0;

  for (int t = 0; t < ntiles; ++t) {
    const int kv0 = t * KVB;
    const bool have_next = (t + 1 < ntiles);
    if (have_next) issue_loads(t + 1);  // overlap with compute below

    unsigned char* Klds = smem + (cur << 15);
    unsigned char* Vlds = Klds + 16384;

    if (t <= myqt) {  // wave-uniform guard; A-waves idle past their diagonal
      // ---- S = Q K^T  (D-layout: row q = 4*lg+i, col kv = 16*nt+lm) ----
      f32x4 s[4];
      #pragma unroll
      for (int nt = 0; nt < 4; ++nt) s[nt] = (f32x4){0.f, 0.f, 0.f, 0.f};
      #pragma unroll
      for (int nt = 0; nt < 4; ++nt) {
        int r = (nt << 4) + lm;
        #pragma unroll
        for (int kc = 0; kc < 4; ++kc) {
          int byte = (r << 8) + (((kc << 6) + (lg << 4)) ^ ((r & 7) << 4));
          bf16x8 kb = *(const bf16x8*)(Klds + byte);
          s[nt] = __builtin_amdgcn_mfma_f32_16x16x32_bf16(qa[kc], kb, s[nt], 0, 0, 0);
        }
      }

      // ---- causal mask (additive -1e9 like the reference) ----
      if (kv0 + KVB - 1 > qbase) {
        #pragma unroll
        for (int nt = 0; nt < 4; ++nt) {
          int col = kv0 + (nt << 4) + lm;
          #pragma unroll
          for (int i = 0; i < 4; ++i) {
            int row = qbase + (lg << 2) + i;
            s[nt][i] += (col > row) ? NEGBIG : 0.f;
          }
        }
      }

      // ---- online softmax: per-lane 4 rows, 16-lane group reduce ----
      float tmax[4];
      #pragma unroll
      for (int i = 0; i < 4; ++i)
        tmax[i] = fmaxf(fmaxf(s[0][i], s[1][i]), fmaxf(s[2][i], s[3][i]));
      #pragma unroll
      for (int d = 1; d < 16; d <<= 1) {
        #pragma unroll
        for (int i = 0; i < 4; ++i)
          tmax[i] = fmaxf(tmax[i], __shfl_xor(tmax[i], d));
      }
      float fac[4];
      #pragma unroll
      for (int i = 0; i < 4; ++i) {
        float mn = fmaxf(mrow[i], tmax[i]);
        fac[i] = __expf(mrow[i] - mn);
        mrow[i] = mn;
      }
      float rsum[4] = {0.f, 0.f, 0.f, 0.f};
      #pragma unroll
      for (int nt = 0; nt < 4; ++nt) {
        #pragma unroll
        for (int i = 0; i < 4; ++i) {
          float pv = __expf(s[nt][i] - mrow[i]);
          s[nt][i] = pv;
          rsum[i] += pv;
        }
      }
      #pragma unroll
      for (int d = 1; d < 16; d <<= 1) {
        #pragma unroll
        for (int i = 0; i < 4; ++i) rsum[i] += __shfl_xor(rsum[i], d);
      }
      #pragma unroll
      for (int i = 0; i < 4; ++i) lrow[i] = lrow[i] * fac[i] + rsum[i];
      #pragma unroll
      for (int nt2 = 0; nt2 < 8; ++nt2) {
        #pragma unroll
        for (int i = 0; i < 4; ++i) o[nt2][i] *= fac[i];
      }

      // ---- P: D-layout -> A-layout via per-wave swizzled LDS ----
      #pragma unroll
      for (int nt = 0; nt < 4; ++nt) {
        int colb = ((nt << 4) + lm) << 1;
        #pragma unroll
        for (int i = 0; i < 4; ++i) {
          int row = (lg << 2) + i;
          *(unsigned short*)(Plds + (row << 7) + (colb ^ ((row & 7) << 4))) =
              f2bf(s[nt][i]);
        }
      }
      asm volatile("s_waitcnt lgkmcnt(0)" ::: "memory");
      bf16x8 pa[2];
      #pragma unroll
      for (int kc = 0; kc < 2; ++kc) {
        int byte = (lm << 7) + (((kc << 6) + (lg << 4)) ^ ((lm & 7) << 4));
        pa[kc] = *(const bf16x8*)(Plds + byte);
      }

      // ---- O += P V  (V^T in LDS gives contiguous-k B-frags) ----
      #pragma unroll
      for (int nt2 = 0; nt2 < 8; ++nt2) {
        int dr = (nt2 << 4) + lm;
        #pragma unroll
        for (int kc = 0; kc < 2; ++kc) {
          int byte = (dr << 7) + (((kc << 6) + (lg << 4)) ^ ((dr & 7) << 4));
          bf16x8 vb = *(const bf16x8*)(Vlds + byte);
          o[nt2] = __builtin_amdgcn_mfma_f32_16x16x32_bf16(pa[kc], vb, o[nt2], 0, 0, 0);
        }
      }
    }

    if (have_next) {
      // stage tile t+1 into the other buffer (no pre-barrier needed: the
      // end-of-previous-iteration barrier guarantees buf[cur^1] is done)
      unsigned char* Kn = smem + ((cur ^ 1) << 15);
      write_lds(Kn, Kn + 16384);
    }
    __syncthreads();
    cur ^= 1;
  }

  // ---- epilogue: O /= l, store f32 ----
  float inv[4];
  #pragma unroll
  for (int i = 0; i < 4; ++i) inv[i] = 1.f / lrow[i];
  #pragma unroll
  for (int nt2 = 0; nt2 < 8; ++nt2) {
    int col = h * HD + (nt2 << 4) + lm;
    #pragma unroll
    for (int i = 0; i < 4; ++i) {
      int row = qbase + (lg << 2) + i;
      out[(size_t)row * ODIM + col] = o[nt2][i] * inv[i];
    }
  }
}

extern "C" void kernel_launch(void* const* d_in, const int* in_sizes, int n_in,
                              void* d_out, int out_size, void* d_ws, size_t ws_size,
                              hipStream_t stream) {
  // inputs: [0]=input_pos(i64) [1]=q(f32) [2]=k(f32) [3]=v(f32)
  //         [4]=bsz [5]=seqlen [6]=mask(f32, pure causal -> computed analytically)
  const float* q = (const float*)d_in[1];
  const float* k = (const float*)d_in[2];
  const float* v = (const float*)d_in[3];
  float* out = (float*)d_out;
  dim3 grid(SEQ / QB / 2, NH);  // 16 balanced Q-tile pairs x 32 heads
  sdpa_flash_kernel<<<grid, 512, 0, stream>>>(q, k, v, out);
}

// Round 8
// 105.281 us; speedup vs baseline: 2.9634x; 2.9634x over previous
//
#include <hip/hip_runtime.h>
#include <hip/hip_bf16.h>

#define SEQ 2048
#define HD 128
#define NH 32
#define NKV 8
#define ODIM 4096
#define QB 64
#define KVB 64
#define SCALE 0.08838834764831845f
#define NEGBIG -1e9f

typedef __attribute__((ext_vector_type(8))) short bf16x8;
typedef __attribute__((ext_vector_type(4))) float f32x4;

__device__ __forceinline__ unsigned short f2bf(float x) {
  union { __hip_bfloat16 b; unsigned short u; } c;
  c.b = __float2bfloat16(x);  // RNE, single HW cvt
  return c.u;
}

__device__ __forceinline__ unsigned pack2bf(float lo, float hi) {
  union { __hip_bfloat162 h; unsigned u; } c;
  c.h = __float22bfloat162_rn(float2{lo, hi});  // x=lo (low 16b), y=hi
  return c.u;
}

// Block p handles Q-tiles {p, 31-p}: balanced 33 compute-units per block.
// 8 waves: w<4 -> tile A (qt=p); w>=4 -> tile B (qt=31-p).
// Swapped-operand MFMA: S^T = mfma(K, Q), O^T = mfma(V, P) -> each lane owns
// one P-row (q = lm); softmax stats are scalars; P stays in registers.
__global__ __launch_bounds__(512, 4) void sdpa_flash_kernel(
    const float* __restrict__ q, const float* __restrict__ k,
    const float* __restrict__ v, float* __restrict__ out) {
  // LDS: K [64][128] bf16 swz (16KB) + V^T [128][64] bf16 swz (16KB)
  __shared__ __align__(16) unsigned char smem[32768];
  unsigned char* Klds = smem;
  unsigned char* Vlds = smem + 16384;
  const int tid = threadIdx.x;
  const int w = tid >> 6;
  const int l = tid & 63;
  const int lm = l & 15;
  const int lg = l >> 4;

  const int p = (int)blockIdx.x;       // 0..15
  const int qtA = p;
  const int qtB = 31 - p;
  const int myqt = (w < 4) ? qtA : qtB;
  const int h = (int)blockIdx.y;
  const int hkv = h >> 2;              // repeat_interleave: kv head = h / 4
  const int qbase = myqt * QB + 16 * (w & 3);
  const int myrow = qbase + lm;        // this lane's q row

  // ---- Q fragments, pre-scaled by 1/sqrt(D) ----
  // lane holds Q[q = lm][d = 32*c + 8*lg + j], j=0..7 contiguous
  bf16x8 qa[4];
  {
    const float* qr = q + ((size_t)(h * SEQ + myrow)) * HD + 8 * lg;
    #pragma unroll
    for (int c = 0; c < 4; ++c) {
      float4 a = *(const float4*)(qr + 32 * c);
      float4 b = *(const float4*)(qr + 32 * c + 4);
      union { unsigned short hh[8]; bf16x8 vv; } pk;
      pk.hh[0] = f2bf(a.x * SCALE); pk.hh[1] = f2bf(a.y * SCALE);
      pk.hh[2] = f2bf(a.z * SCALE); pk.hh[3] = f2bf(a.w * SCALE);
      pk.hh[4] = f2bf(b.x * SCALE); pk.hh[5] = f2bf(b.y * SCALE);
      pk.hh[6] = f2bf(b.z * SCALE); pk.hh[7] = f2bf(b.w * SCALE);
      qa[c] = pk.vv;
    }
  }

  // O^T accumulator: o[nt2][i] = O[q=lm][d = 16*nt2 + 4*lg + i]
  f32x4 o[8];
  #pragma unroll
  for (int i = 0; i < 8; ++i) o[i] = (f32x4){0.f, 0.f, 0.f, 0.f};
  float mrow = -1e30f;
  float lrow = 0.f;

  const int ntiles = qtB + 1;  // union of both halves' needs
  const float* kg0 = k + (size_t)hkv * SEQ * HD;
  const float* vg0 = v + (size_t)hkv * SEQ * HD;

  for (int t = 0; t < ntiles; ++t) {
    const int kv0 = t * KVB;
    __syncthreads();  // previous tile's LDS reads complete

    // ---- stage K tile: [kv][d] bf16, b128 writes, XOR-swizzled ----
    {
      const float* kg = kg0 + (size_t)kv0 * HD;
      #pragma unroll
      for (int it = 0; it < 2; ++it) {
        int idx = it * 512 + tid;   // 0..1023
        int r = idx >> 4;           // kv row 0..63
        int c8 = (idx & 15) << 3;   // d start
        const float* src = kg + r * HD + c8;
        float4 a = *(const float4*)(src);
        float4 b = *(const float4*)(src + 4);
        union { unsigned short hh[8]; uint4 u4; } pk;
        pk.hh[0]=f2bf(a.x); pk.hh[1]=f2bf(a.y); pk.hh[2]=f2bf(a.z); pk.hh[3]=f2bf(a.w);
        pk.hh[4]=f2bf(b.x); pk.hh[5]=f2bf(b.y); pk.hh[6]=f2bf(b.z); pk.hh[7]=f2bf(b.w);
        int byte = (r << 8) + ((c8 << 1) ^ ((r & 7) << 4));
        *(uint4*)(Klds + byte) = pk.u4;
      }
      // ---- stage V^T: [d][kv] bf16, packed kv-pair b32 writes ----
      const float* vg = vg0 + (size_t)kv0 * HD;
      {
        int rr = (tid & 31) << 1;    // even kv row
        int db = tid >> 5;           // d-block 0..15
        const float* s0 = vg + rr * HD + (db << 3);
        const float* s1 = s0 + HD;
        float4 a0 = *(const float4*)(s0);
        float4 b0 = *(const float4*)(s0 + 4);
        float4 a1 = *(const float4*)(s1);
        float4 b1 = *(const float4*)(s1 + 4);
        float lo[8] = {a0.x,a0.y,a0.z,a0.w,b0.x,b0.y,b0.z,b0.w};
        float hi[8] = {a1.x,a1.y,a1.z,a1.w,b1.x,b1.y,b1.z,b1.w};
        #pragma unroll
        for (int j = 0; j < 8; ++j) {
          int d = (db << 3) + j;
          int byte = (d << 7) + ((rr << 1) ^ ((d & 7) << 4));
          *(unsigned*)(Vlds + byte) = pack2bf(lo[j], hi[j]);
        }
      }
    }
    __syncthreads();

    if (t <= myqt) {  // wave-uniform guard; A-waves idle past their diagonal
      // ---- S^T = K Q^T : s[nt][i] = S[q=lm][kv = kv0 + 16*nt + 4*lg + i] ----
      f32x4 s[4];
      #pragma unroll
      for (int nt = 0; nt < 4; ++nt) s[nt] = (f32x4){0.f, 0.f, 0.f, 0.f};
      #pragma unroll
      for (int nt = 0; nt < 4; ++nt) {
        int r = (nt << 4) + lm;
        #pragma unroll
        for (int kc = 0; kc < 4; ++kc) {
          int byte = (r << 8) + (((kc << 6) + (lg << 4)) ^ ((r & 7) << 4));
          bf16x8 kb = *(const bf16x8*)(Klds + byte);
          s[nt] = __builtin_amdgcn_mfma_f32_16x16x32_bf16(kb, qa[kc], s[nt], 0, 0, 0);
        }
      }

      // ---- causal mask (additive -1e9 like the reference) ----
      if (kv0 + KVB - 1 > qbase) {
        #pragma unroll
        for (int nt = 0; nt < 4; ++nt) {
          #pragma unroll
          for (int i = 0; i < 4; ++i) {
            int col = kv0 + (nt << 4) + (lg << 2) + i;
            s[nt][i] += (col > myrow) ? NEGBIG : 0.f;
          }
        }
      }

      // ---- online softmax: lane owns row q=lm; reduce over 4 lanes ----
      float tm = -1e30f;
      #pragma unroll
      for (int nt = 0; nt < 4; ++nt)
        #pragma unroll
        for (int i = 0; i < 4; ++i) tm = fmaxf(tm, s[nt][i]);
      tm = fmaxf(tm, __shfl_xor(tm, 16));
      tm = fmaxf(tm, __shfl_xor(tm, 32));
      float mn = fmaxf(mrow, tm);
      float fac = __expf(mrow - mn);
      mrow = mn;
      float rs = 0.f;
      #pragma unroll
      for (int nt = 0; nt < 4; ++nt) {
        #pragma unroll
        for (int i = 0; i < 4; ++i) {
          float pv = __expf(s[nt][i] - mn);
          s[nt][i] = pv;
          rs += pv;
        }
      }
      rs += __shfl_xor(rs, 16);
      rs += __shfl_xor(rs, 32);
      lrow = lrow * fac + rs;
      #pragma unroll
      for (int nt2 = 0; nt2 < 8; ++nt2) {
        #pragma unroll
        for (int i = 0; i < 4; ++i) o[nt2][i] *= fac;
      }

      // ---- P^T B-frags fully in-register via pack + lane exchange ----
      // lane needs P[q=lm][kv = 32*kc + 8*lg + j], j=0..7
      unsigned pk0[4], pk1[4];
      #pragma unroll
      for (int nt = 0; nt < 4; ++nt) {
        pk0[nt] = pack2bf(s[nt][0], s[nt][1]);
        pk1[nt] = pack2bf(s[nt][2], s[nt][3]);
      }
      const int srcA = lm + ((lg & 1) << 5);  // lane group g_a = 2*(lg&1)
      const int srcB = srcA + 16;             // g_b = g_a + 1
      const bool lo2 = (lg < 2);
      bf16x8 pb[2];
      #pragma unroll
      for (int kc = 0; kc < 2; ++kc) {
        int a0 = __shfl((int)pk0[2*kc], srcA), b0 = __shfl((int)pk0[2*kc+1], srcA);
        int a1 = __shfl((int)pk1[2*kc], srcA), b1 = __shfl((int)pk1[2*kc+1], srcA);
        int a2 = __shfl((int)pk0[2*kc], srcB), b2 = __shfl((int)pk0[2*kc+1], srcB);
        int a3 = __shfl((int)pk1[2*kc], srcB), b3 = __shfl((int)pk1[2*kc+1], srcB);
        union { int u[4]; bf16x8 v; } pw;
        pw.u[0] = lo2 ? a0 : b0;  // kv 8lg+{0,1}
        pw.u[1] = lo2 ? a1 : b1;  // kv 8lg+{2,3}
        pw.u[2] = lo2 ? a2 : b2;  // kv 8lg+{4,5}
        pw.u[3] = lo2 ? a3 : b3;  // kv 8lg+{6,7}
        pb[kc] = pw.v;
      }

      // ---- O^T += V^T P^T  (V^T LDS rows feed the A operand) ----
      #pragma unroll
      for (int nt2 = 0; nt2 < 8; ++nt2) {
        int dr = (nt2 << 4) + lm;
        #pragma unroll
        for (int kc = 0; kc < 2; ++kc) {
          int byte = (dr << 7) + (((kc << 6) + (lg << 4)) ^ ((dr & 7) << 4));
          bf16x8 vb = *(const bf16x8*)(Vlds + byte);
          o[nt2] = __builtin_amdgcn_mfma_f32_16x16x32_bf16(vb, pb[kc], o[nt2], 0, 0, 0);
        }
      }
    }
  }

  // ---- epilogue: O /= l, coalesced float4 stores ----
  float inv = 1.f / lrow;
  float* orow = out + (size_t)myrow * ODIM + h * HD + (lg << 2);
  #pragma unroll
  for (int nt2 = 0; nt2 < 8; ++nt2) {
    float4 st = {o[nt2][0] * inv, o[nt2][1] * inv, o[nt2][2] * inv, o[nt2][3] * inv};
    *(float4*)(orow + (nt2 << 4)) = st;
  }
}

extern "C" void kernel_launch(void* const* d_in, const int* in_sizes, int n_in,
                              void* d_out, int out_size, void* d_ws, size_t ws_size,
                              hipStream_t stream) {
  // inputs: [0]=input_pos(i64) [1]=q(f32) [2]=k(f32) [3]=v(f32)
  //         [4]=bsz [5]=seqlen [6]=mask(f32, pure causal -> computed analytically)
  const float* q = (const float*)d_in[1];
  const float* k = (const float*)d_in[2];
  const float* v = (const float*)d_in[3];
  float* out = (float*)d_out;
  dim3 grid(SEQ / QB / 2, NH);  // 16 balanced Q-tile pairs x 32 heads
  sdpa_flash_kernel<<<grid, 512, 0, stream>>>(q, k, v, out);
}